// Round 2
// baseline (420.425 us; speedup 1.0000x reference)
//
#include <hip/hip_runtime.h>

#define NB    4096      // histogram buckets over [0,1)
#define CAPL  1024      // per-batch candidate capacity in LDS (expected ~64)
#define BATCH 32
#define NTOK  262144    // 512*512
#define LOSS_BLOCKS 4096
#define LOSS_THREADS 256
// tokens per thread in loss = BATCH*NTOK / (LOSS_BLOCKS*LOSS_THREADS) = 8

__device__ __forceinline__ int bucket_of(float v) {
    int b = (int)(v * (float)NB);
    return b > NB - 1 ? NB - 1 : b;
}

// --- Pass 1: FULL per-batch selection in one block (hist+select+collect+refine).
// One block per batch; everything lives in LDS; no global hist, no memset.
__global__ __launch_bounds__(1024) void select_kernel(
        const float* __restrict__ smap, const int* __restrict__ kptr,
        float* __restrict__ T, int* __restrict__ ncut, int* __restrict__ done) {
    __shared__ int   lh[NB];          // 16 KB histogram
    __shared__ int   suf[1024 + 1];   // suffix-scan of 4-bucket chunk sums
    __shared__ float cv[CAPL];
    __shared__ int   ci[CAPL];
    __shared__ int   s_cnt, s_tb, s_R;
    const int b = blockIdx.x;
    const int t = threadIdx.x;
    if (t == 0) { s_cnt = 0; if (b == 0) *done = 0; }  // arm loss_kernel's flag
    for (int i = t; i < NB; i += 1024) lh[i] = 0;
    __syncthreads();

    const float4* src = (const float4*)(smap + (size_t)b * NTOK);
    // 65536 float4 per batch, 64 per thread, unit-stride coalesced
    #pragma unroll 4
    for (int k = 0; k < 64; k++) {
        float4 v = src[t + k * 1024];
        atomicAdd(&lh[bucket_of(v.x)], 1);
        atomicAdd(&lh[bucket_of(v.y)], 1);
        atomicAdd(&lh[bucket_of(v.z)], 1);
        atomicAdd(&lh[bucket_of(v.w)], 1);
    }
    __syncthreads();

    // chunk sums (4 buckets/thread), then Hillis-Steele inclusive SUFFIX scan
    const int base = t * 4;
    int c = lh[base] + lh[base + 1] + lh[base + 2] + lh[base + 3];
    suf[t] = c;
    if (t == 0) suf[1024] = 0;   // sentinel for t==1023
    __syncthreads();
    for (int off = 1; off < 1024; off <<= 1) {
        int v = suf[t] + ((t + off < 1024) ? suf[t + off] : 0);
        __syncthreads();
        suf[t] = v;
        __syncthreads();
    }
    const int K = *kptr;
    {
        int cum = suf[t + 1];   // elements in buckets strictly above this chunk
        #pragma unroll
        for (int i = 3; i >= 0; i--) {
            int hb = lh[base + i];
            if (cum < K && cum + hb >= K) { s_tb = base + i; s_R = K - cum; }
            cum += hb;
        }
    }
    __syncthreads();
    const int tb = s_tb;

    // collect candidates from threshold bucket (re-read is L2-hot: 1 MB/block)
    #pragma unroll 4
    for (int k = 0; k < 64; k++) {
        int fi = t + k * 1024;
        float4 v = src[fi];
        float vals[4] = {v.x, v.y, v.z, v.w};
        #pragma unroll
        for (int s = 0; s < 4; s++) {
            if (bucket_of(vals[s]) == tb) {
                int p = atomicAdd(&s_cnt, 1);
                if (p < CAPL) { cv[p] = vals[s]; ci[p] = 4 * fi + s; }
            }
        }
    }
    __syncthreads();

    // exact rank-(R-1) under (value desc, index asc)
    int M = s_cnt, R = s_R;
    bool overflow = (M > CAPL);
    if (M > CAPL) M = CAPL;
    if (overflow || R > M || R < 1) {
        if (t == 0) { T[b] = (float)tb / (float)NB; ncut[b] = 0x7fffffff; }
        return;
    }
    for (int i = t; i < M; i += 1024) {
        float vi = cv[i]; int ii = ci[i];
        int r = 0;
        for (int j = 0; j < M; j++) {
            float vj = cv[j];
            r += (vj > vi) || (vj == vi && ci[j] < ii);
        }
        if (r == R - 1) { T[b] = vi; ncut[b] = ii; }   // unique rank -> single writer
    }
}

__device__ __forceinline__ float token_loss(float d0, float d1, float u0, float u1,
                                            bool sel) {
    float g0 = -__logf(-__logf(u0));
    float g1 = -__logf(-__logf(u1));
    float dd = (d0 + g0) - (d1 + g1);
    float l  = __logf(1.f + __expf(-fabsf(dd)));
    float lp0 = (dd >= 0.f) ? -l      : dd - l;
    float lp1 = (dd >= 0.f) ? -l - dd : -l;
    lp0 = fmaxf(lp0, -100.f); lp1 = fmaxf(lp1, -100.f);
    return sel ? -lp0 : -lp1;
}

// --- Pass 2: fused loss, 8 tokens/thread, all streams unit-stride.
// Final reduction folded in via last-block-done (device-scope atomic + fences).
__global__ __launch_bounds__(256) void loss_kernel(
        const float* __restrict__ ds, const float* __restrict__ u,
        const float* __restrict__ smap, const float* __restrict__ T,
        const int* __restrict__ ncut, float* __restrict__ partials,
        int* __restrict__ done, float* __restrict__ out) {
    const int b = blockIdx.x >> 7;                       // 128 blocks per batch
    const int q = ((blockIdx.x & 127) << 8) | threadIdx.x; // [0, 32768) pair-group id
    const int PSTR = 32768;                              // pairs-per-chunk stride
    const float4* ds4 = (const float4*)(ds + (size_t)b * NTOK * 2);
    const float4* u4  = (const float4*)(u  + (size_t)b * NTOK * 2);
    const float2* s2  = (const float2*)(smap + (size_t)b * NTOK);
    const float Tb = T[b];
    const int   nc = ncut[b];

    // issue all loads first (12 unit-stride streams) for latency overlap
    float4 dA = ds4[q];            float4 dB = ds4[q + PSTR];
    float4 dC = ds4[q + 2*PSTR];   float4 dD = ds4[q + 3*PSTR];
    float4 uA = u4[q];             float4 uB = u4[q + PSTR];
    float4 uC = u4[q + 2*PSTR];    float4 uD = u4[q + 3*PSTR];
    float2 sA = s2[q];             float2 sB = s2[q + PSTR];
    float2 sC = s2[q + 2*PSTR];    float2 sD = s2[q + 3*PSTR];

    float acc = 0.f;
    {   int n = 2 * q;              // pair q -> tokens n, n+1
        bool a = (sA.x > Tb) || (sA.x == Tb && n     <= nc);
        bool c = (sA.y > Tb) || (sA.y == Tb && n + 1 <= nc);
        acc += token_loss(dA.x, dA.y, uA.x, uA.y, a)
             + token_loss(dA.z, dA.w, uA.z, uA.w, c);
    }
    {   int n = 2 * (q + PSTR);
        bool a = (sB.x > Tb) || (sB.x == Tb && n     <= nc);
        bool c = (sB.y > Tb) || (sB.y == Tb && n + 1 <= nc);
        acc += token_loss(dB.x, dB.y, uB.x, uB.y, a)
             + token_loss(dB.z, dB.w, uB.z, uB.w, c);
    }
    {   int n = 2 * (q + 2*PSTR);
        bool a = (sC.x > Tb) || (sC.x == Tb && n     <= nc);
        bool c = (sC.y > Tb) || (sC.y == Tb && n + 1 <= nc);
        acc += token_loss(dC.x, dC.y, uC.x, uC.y, a)
             + token_loss(dC.z, dC.w, uC.z, uC.w, c);
    }
    {   int n = 2 * (q + 3*PSTR);
        bool a = (sD.x > Tb) || (sD.x == Tb && n     <= nc);
        bool c = (sD.y > Tb) || (sD.y == Tb && n + 1 <= nc);
        acc += token_loss(dD.x, dD.y, uD.x, uD.y, a)
             + token_loss(dD.z, dD.w, uD.z, uD.w, c);
    }

    // block reduce: wave(64) shfl, then cross-wave LDS
    for (int off = 32; off > 0; off >>= 1) acc += __shfl_down(acc, off, 64);
    __shared__ float red[4];
    __shared__ int s_last;
    const int lane = threadIdx.x & 63, wv = threadIdx.x >> 6;
    if (lane == 0) red[wv] = acc;
    __syncthreads();
    if (threadIdx.x == 0) {
        partials[blockIdx.x] = red[0] + red[1] + red[2] + red[3];
        __threadfence();                          // publish partial device-wide
        int old = atomicAdd(done, 1);             // device-scope by default
        s_last = (old == LOSS_BLOCKS - 1) ? 1 : 0;
    }
    __syncthreads();
    if (s_last) {
        __threadfence();                          // acquire all partials
        const int t = threadIdx.x;
        float s = 0.f;
        #pragma unroll
        for (int j = 0; j < 16; j++) s += partials[t * 16 + j];  // deterministic order
        for (int off = 32; off > 0; off >>= 1) s += __shfl_down(s, off, 64);
        __shared__ float fr[4];
        if (lane == 0) fr[wv] = s;
        __syncthreads();
        if (t == 0) out[0] = fr[0] + fr[1] + fr[2] + fr[3];
    }
}

extern "C" void kernel_launch(void* const* d_in, const int* in_sizes, int n_in,
                              void* d_out, int out_size, void* d_ws, size_t ws_size,
                              hipStream_t stream) {
    const float* ds   = (const float*)d_in[0];   // [B, N, 2]
    const float* smap = (const float*)d_in[1];   // [B, 1, H, W] == [B, N]
    const float* u    = (const float*)d_in[2];   // [B, N, 2]
    const int*   kptr = (const int*)d_in[3];     // scalar K

    // workspace: T[32] | ncut[32] | partials[4096] | done[1]
    float* T        = (float*)d_ws;
    int*   ncut     = (int*)(T + BATCH);
    float* partials = (float*)(ncut + BATCH);
    int*   done     = (int*)(partials + LOSS_BLOCKS);

    select_kernel<<<BATCH, 1024, 0, stream>>>(smap, kptr, T, ncut, done);
    loss_kernel<<<LOSS_BLOCKS, LOSS_THREADS, 0, stream>>>(ds, u, smap, T, ncut,
                                                          partials, done, (float*)d_out);
}

// Round 3
// 214.213 us; speedup vs baseline: 1.9627x; 1.9627x over previous
//
#include <hip/hip_runtime.h>

#define NB    4096      // histogram buckets over [0,1)
#define CAPL  1024      // per-batch candidate capacity in LDS (expected ~64)
#define BATCH 32
#define NTOK  262144    // 512*512
#define HB_PER_BATCH 8
#define HIST_BLOCKS  (BATCH * HB_PER_BATCH)   // 256
#define LOSS_BLOCKS  4096                     // 128 blocks/batch, 8 tokens/thread
#define LOSS_THREADS 256

__device__ __forceinline__ int bucket_of(float v) {
    int b = (int)(v * (float)NB);
    return b > NB - 1 ? NB - 1 : b;
}

// --- Pass 1: per-block partial histograms (non-atomic global write, no memset).
// 256 blocks x 1024 threads, 8 blocks per batch, each block owns a 128KB chunk.
__global__ __launch_bounds__(1024) void hist_kernel(const float* __restrict__ smap,
                                                    unsigned short* __restrict__ hist_part) {
    __shared__ int lh[NB];
    for (int i = threadIdx.x; i < NB; i += 1024) lh[i] = 0;
    __syncthreads();
    const int b  = blockIdx.x >> 3;
    const int cb = blockIdx.x & 7;
    const int chunk = NTOK / HB_PER_BATCH;         // 32768 floats
    const float4* src = (const float4*)(smap + (size_t)b * NTOK + (size_t)cb * chunk);
    const int nf4 = chunk / 4;                     // 8192
    for (int i = threadIdx.x; i < nf4; i += 1024) {
        float4 v = src[i];
        atomicAdd(&lh[bucket_of(v.x)], 1);
        atomicAdd(&lh[bucket_of(v.y)], 1);
        atomicAdd(&lh[bucket_of(v.z)], 1);
        atomicAdd(&lh[bucket_of(v.w)], 1);
    }
    __syncthreads();
    unsigned short* dst = hist_part + (size_t)blockIdx.x * NB;
    for (int i = threadIdx.x; i < NB; i += 1024)
        dst[i] = (unsigned short)lh[i];            // block sees 32768 vals: fits u16
}

// --- Pass 2: per-batch select + collect + refine (one block per batch).
// Heavy atomic work is gone (hist comes from partials); collect re-read is L3-hot.
__global__ __launch_bounds__(1024) void selref_kernel(
        const float* __restrict__ smap, const unsigned short* __restrict__ hist_part,
        const int* __restrict__ kptr, float* __restrict__ T, int* __restrict__ ncut) {
    __shared__ int   lh[NB];          // 16 KB summed histogram
    __shared__ int   suf[1024 + 1];   // suffix-scan of 4-bucket chunk sums
    __shared__ float cv[CAPL];
    __shared__ int   ci[CAPL];
    __shared__ int   s_cnt, s_tb, s_R;
    const int b = blockIdx.x;
    const int t = threadIdx.x;
    if (t == 0) s_cnt = 0;

    // sum the 8 partial histograms for this batch
    const unsigned short* hp = hist_part + (size_t)b * HB_PER_BATCH * NB;
    for (int i = t; i < NB; i += 1024) {
        int s = 0;
        #pragma unroll
        for (int p = 0; p < HB_PER_BATCH; p++) s += hp[p * NB + i];
        lh[i] = s;
    }
    __syncthreads();

    // chunk sums (4 buckets/thread) -> Hillis-Steele inclusive SUFFIX scan
    const int base = t * 4;
    int c = lh[base] + lh[base + 1] + lh[base + 2] + lh[base + 3];
    suf[t] = c;
    if (t == 0) suf[1024] = 0;
    __syncthreads();
    for (int off = 1; off < 1024; off <<= 1) {
        int v = suf[t] + ((t + off < 1024) ? suf[t + off] : 0);
        __syncthreads();
        suf[t] = v;
        __syncthreads();
    }
    const int K = *kptr;
    {
        int cum = suf[t + 1];   // elements in buckets strictly above this chunk
        #pragma unroll
        for (int i = 3; i >= 0; i--) {
            int hb = lh[base + i];
            if (cum < K && cum + hb >= K) { s_tb = base + i; s_R = K - cum; }
            cum += hb;
        }
    }
    __syncthreads();
    const int tb = s_tb;

    // collect candidates in threshold bucket (re-read 1MB, L3-resident after pass 1)
    const float4* src = (const float4*)(smap + (size_t)b * NTOK);
    #pragma unroll 4
    for (int k = 0; k < 64; k++) {
        int fi = t + k * 1024;
        float4 v = src[fi];
        float vals[4] = {v.x, v.y, v.z, v.w};
        #pragma unroll
        for (int s = 0; s < 4; s++) {
            if (bucket_of(vals[s]) == tb) {
                int p = atomicAdd(&s_cnt, 1);
                if (p < CAPL) { cv[p] = vals[s]; ci[p] = 4 * fi + s; }
            }
        }
    }
    __syncthreads();

    // exact rank-(R-1) under (value desc, index asc)
    int M = s_cnt, R = s_R;
    bool overflow = (M > CAPL);
    if (M > CAPL) M = CAPL;
    if (overflow || R > M || R < 1) {
        if (t == 0) { T[b] = (float)tb / (float)NB; ncut[b] = 0x7fffffff; }
        return;
    }
    for (int i = t; i < M; i += 1024) {
        float vi = cv[i]; int ii = ci[i];
        int r = 0;
        for (int j = 0; j < M; j++) {
            float vj = cv[j];
            r += (vj > vi) || (vj == vi && ci[j] < ii);
        }
        if (r == R - 1) { T[b] = vi; ncut[b] = ii; }   // unique rank -> single writer
    }
}

__device__ __forceinline__ float token_loss(float d0, float d1, float u0, float u1,
                                            bool sel) {
    float g0 = -__logf(-__logf(u0));
    float g1 = -__logf(-__logf(u1));
    float dd = (d0 + g0) - (d1 + g1);
    float l  = __logf(1.f + __expf(-fabsf(dd)));
    float lp0 = (dd >= 0.f) ? -l      : dd - l;
    float lp1 = (dd >= 0.f) ? -l - dd : -l;
    lp0 = fmaxf(lp0, -100.f); lp1 = fmaxf(lp1, -100.f);
    return sel ? -lp0 : -lp1;
}

// --- Pass 3: fused loss, 8 tokens/thread (10 in-flight loads for latency hiding),
// consecutive per-thread addressing (proven round-1 pattern class). Plain stores.
__global__ __launch_bounds__(256) void loss_kernel(
        const float* __restrict__ ds, const float* __restrict__ u,
        const float* __restrict__ smap, const float* __restrict__ T,
        const int* __restrict__ ncut, float* __restrict__ partials) {
    const int b = blockIdx.x >> 7;                          // 128 blocks per batch
    const int r = ((blockIdx.x & 127) << 8) | threadIdx.x;  // [0, 32768): 8-token group
    const float4* ds4 = (const float4*)(ds + (size_t)b * NTOK * 2) + 4 * (size_t)r;
    const float4* u4  = (const float4*)(u  + (size_t)b * NTOK * 2) + 4 * (size_t)r;
    const float4* s4  = (const float4*)(smap + (size_t)b * NTOK) + 2 * (size_t)r;

    // issue all 10 loads up-front
    float4 d0 = ds4[0], d1 = ds4[1], d2 = ds4[2], d3 = ds4[3];
    float4 w0 = u4[0],  w1 = u4[1],  w2 = u4[2],  w3 = u4[3];
    float4 sA = s4[0],  sB = s4[1];
    const float Tb = T[b];
    const int   nc = ncut[b];
    const int   n0 = r << 3;   // first token index

    bool e0 = (sA.x > Tb) || (sA.x == Tb && (n0 + 0) <= nc);
    bool e1 = (sA.y > Tb) || (sA.y == Tb && (n0 + 1) <= nc);
    bool e2 = (sA.z > Tb) || (sA.z == Tb && (n0 + 2) <= nc);
    bool e3 = (sA.w > Tb) || (sA.w == Tb && (n0 + 3) <= nc);
    bool e4 = (sB.x > Tb) || (sB.x == Tb && (n0 + 4) <= nc);
    bool e5 = (sB.y > Tb) || (sB.y == Tb && (n0 + 5) <= nc);
    bool e6 = (sB.z > Tb) || (sB.z == Tb && (n0 + 6) <= nc);
    bool e7 = (sB.w > Tb) || (sB.w == Tb && (n0 + 7) <= nc);

    float acc = token_loss(d0.x, d0.y, w0.x, w0.y, e0)
              + token_loss(d0.z, d0.w, w0.z, w0.w, e1)
              + token_loss(d1.x, d1.y, w1.x, w1.y, e2)
              + token_loss(d1.z, d1.w, w1.z, w1.w, e3)
              + token_loss(d2.x, d2.y, w2.x, w2.y, e4)
              + token_loss(d2.z, d2.w, w2.z, w2.w, e5)
              + token_loss(d3.x, d3.y, w3.x, w3.y, e6)
              + token_loss(d3.z, d3.w, w3.z, w3.w, e7);

    // wave(64) reduce, then cross-wave via LDS, one partial write per block
    for (int off = 32; off > 0; off >>= 1) acc += __shfl_down(acc, off, 64);
    __shared__ float red[4];
    const int lane = threadIdx.x & 63, wv = threadIdx.x >> 6;
    if (lane == 0) red[wv] = acc;
    __syncthreads();
    if (threadIdx.x == 0)
        partials[blockIdx.x] = red[0] + red[1] + red[2] + red[3];
}

// --- Pass 4: reduce LOSS_BLOCKS partials into out[0] (single block) ---
__global__ __launch_bounds__(1024) void reduce_kernel(const float* __restrict__ partials,
                                                      float* __restrict__ out) {
    float acc = 0.f;
    for (int i = threadIdx.x; i < LOSS_BLOCKS; i += 1024) acc += partials[i];
    for (int off = 32; off > 0; off >>= 1) acc += __shfl_down(acc, off, 64);
    __shared__ float red[16];
    const int lane = threadIdx.x & 63, wv = threadIdx.x >> 6;
    if (lane == 0) red[wv] = acc;
    __syncthreads();
    if (threadIdx.x == 0) {
        float s = 0.f;
        for (int w = 0; w < 16; w++) s += red[w];
        out[0] = s;
    }
}

extern "C" void kernel_launch(void* const* d_in, const int* in_sizes, int n_in,
                              void* d_out, int out_size, void* d_ws, size_t ws_size,
                              hipStream_t stream) {
    const float* ds   = (const float*)d_in[0];   // [B, N, 2]
    const float* smap = (const float*)d_in[1];   // [B, 1, H, W] == [B, N]
    const float* u    = (const float*)d_in[2];   // [B, N, 2]
    const int*   kptr = (const int*)d_in[3];     // scalar K

    // workspace: hist_part[256*4096 u16 = 2MB] | T[32] | ncut[32] | partials[4096]
    unsigned short* hist_part = (unsigned short*)d_ws;
    float* T        = (float*)(hist_part + (size_t)HIST_BLOCKS * NB);
    int*   ncut     = (int*)(T + BATCH);
    float* partials = (float*)(ncut + BATCH);

    hist_kernel<<<HIST_BLOCKS, 1024, 0, stream>>>(smap, hist_part);
    selref_kernel<<<BATCH, 1024, 0, stream>>>(smap, hist_part, kptr, T, ncut);
    loss_kernel<<<LOSS_BLOCKS, LOSS_THREADS, 0, stream>>>(ds, u, smap, T, ncut, partials);
    reduce_kernel<<<1, 1024, 0, stream>>>(partials, (float*)d_out);
}